// Round 1
// baseline (378.263 us; speedup 1.0000x reference)
//
#include <hip/hip_runtime.h>
#include <stdint.h>

// Problem constants (from reference setup_inputs)
#define B_    64
#define T_    4096
#define D_    256
#define A_    50
#define APAD  64     // A padded to 4 MFMA n-tiles of 16 (cols 50..63 zeroed)
#define TB    256    // T-rows per block
#define ST    32     // T-rows per subtile (2 MFMA m-tiles)
#define WT_STRIDE 264  // bf16 elems per padded row (528B = 132 words -> bank-uniform b128 reads)
#define XS_STRIDE 264
#define EPS_  1e-7f

// ws float layout:
//   [0      .. 16383]  num accumulator [64][256]
//   [16384 .. 16447]   den accumulator [64]
//   [16448 .. 16511]   b padded to 64
//   [16512 .. 16575]   u padded to 64
//   [16576 .. ]        Wt bf16 [64][WT_STRIDE]  (33792 bytes)
#define OFF_NUM 0
#define OFF_DEN 16384
#define OFF_B   16448
#define OFF_U   16512
#define OFF_WT  16576

typedef __attribute__((ext_vector_type(8))) short short8;
typedef __attribute__((ext_vector_type(4))) float floatx4;

__device__ __forceinline__ unsigned short f32_to_bf16(float f) {
    union { float f; uint32_t u; } v; v.f = f;
    uint32_t u = v.u;
    uint32_t r = u + 0x7FFFu + ((u >> 16) & 1u);   // RNE (inputs finite, no NaN handling needed)
    return (unsigned short)(r >> 16);
}

__device__ __forceinline__ float fast_tanh(float x) {
    float e2 = __expf(2.0f * x);
    return (e2 - 1.0f) * __builtin_amdgcn_rcpf(e2 + 1.0f);
}

// ---------------- prologue: zero accumulators, pack W/b/u ----------------
__global__ void att_prologue(const float* __restrict__ W,
                             const float* __restrict__ bias,
                             const float* __restrict__ u,
                             float* __restrict__ ws) {
    int idx = blockIdx.x * blockDim.x + threadIdx.x;
    int stride = gridDim.x * blockDim.x;
    // zero num+den
    for (int i = idx; i < OFF_DEN + B_; i += stride) ws[i] = 0.0f;
    // padded b, u
    for (int i = idx; i < APAD; i += stride) {
        ws[OFF_B + i] = (i < A_) ? bias[i] : 0.0f;
        ws[OFF_U + i] = (i < A_) ? u[i]    : 0.0f;
    }
    // W [256][50] fp32 -> Wt bf16 [64][WT_STRIDE] (transposed, col-padded with 0)
    unsigned short* wt = (unsigned short*)(ws + OFF_WT);
    for (int i = idx; i < APAD * D_; i += stride) {
        int a = i >> 8;          // 0..63
        int k = i & 255;         // 0..255
        float val = (a < A_) ? W[k * A_ + a] : 0.0f;
        wt[a * WT_STRIDE + k] = f32_to_bf16(val);
    }
}

// ---------------- main fused kernel ----------------
__global__ __launch_bounds__(256) void att_main(const float* __restrict__ x,
                                                float* __restrict__ ws) {
    __shared__ unsigned short lds_wt[APAD * WT_STRIDE];  // 33792 B
    __shared__ unsigned short lds_x[ST * XS_STRIDE];     // 16896 B
    __shared__ float part[ST][2];
    __shared__ float e_lds[ST];

    const int tid  = threadIdx.x;
    const int wave = tid >> 6;
    const int lane = tid & 63;
    const int bb   = blockIdx.y;   // batch
    const int tblk = blockIdx.x;   // T-tile

    // stage packed Wt (bf16 image, contiguous) into LDS: 33792 B = 2112 uint4
    {
        const uint4* g = (const uint4*)(ws + OFF_WT);
        uint4* l = (uint4*)lds_wt;
        for (int i = tid; i < (APAD * WT_STRIDE * 2) / 16; i += 256) l[i] = g[i];
    }

    // per-wave tile assignment: mt = m-tile (rows), nt0/nt1 = n-tiles (cols)
    const int mt  = wave & 1;
    const int nt0 = (wave >> 1) * 2, nt1 = nt0 + 1;
    const int c0  = nt0 * 16 + (lane & 15);
    const int c1  = nt1 * 16 + (lane & 15);
    const float b0 = ws[OFF_B + c0], b1 = ws[OFF_B + c1];
    const float u0 = ws[OFF_U + c0], u1 = ws[OFF_U + c1];

    float num_acc = 0.0f;   // thread tid owns output column d = tid
    float den_acc = 0.0f;   // only tid < ST accumulate

    const float* xblk = x + ((size_t)bb * T_ + (size_t)tblk * TB) * D_;

    const int arow_off = (mt * 16 + (lane & 15)) * XS_STRIDE;
    const int koff     = (lane >> 4) * 8;
    const int brow0    = (nt0 * 16 + (lane & 15)) * WT_STRIDE;
    const int brow1    = (nt1 * 16 + (lane & 15)) * WT_STRIDE;

    for (int st = 0; st < TB / ST; ++st) {
        __syncthreads();  // S0: protect lds_x vs previous iteration's phase-2 readers (also covers Wt on st=0)

        // ---- phase 1: global fp32 -> bf16 LDS tile (32 rows x 256 cols) ----
        const float4* xg = (const float4*)(xblk + st * ST * D_);
        #pragma unroll
        for (int i = 0; i < 8; ++i) {
            int f = tid + (i << 8);          // float4 index in tile
            float4 v = xg[f];
            int row = f >> 6;                // = wave + 4*i
            int col4 = f & 63;               // = lane
            uint32_t p0 = ((uint32_t)f32_to_bf16(v.y) << 16) | f32_to_bf16(v.x);
            uint32_t p1 = ((uint32_t)f32_to_bf16(v.w) << 16) | f32_to_bf16(v.z);
            uint32_t* dst = (uint32_t*)&lds_x[row * XS_STRIDE + col4 * 4];
            dst[0] = p0; dst[1] = p1;
        }
        __syncthreads();  // S1: x tile ready

        // ---- MFMA: preact[32 x 64] = x_tile[32x256] * Wt^T ----
        floatx4 acc0 = {0.f, 0.f, 0.f, 0.f};
        floatx4 acc1 = {0.f, 0.f, 0.f, 0.f};
        #pragma unroll
        for (int ks = 0; ks < 8; ++ks) {
            short8 a  = *(const short8*)&lds_x[arow_off + ks * 32 + koff];
            short8 w0 = *(const short8*)&lds_wt[brow0 + ks * 32 + koff];
            short8 w1 = *(const short8*)&lds_wt[brow1 + ks * 32 + koff];
            acc0 = __builtin_amdgcn_mfma_f32_16x16x32_bf16(a, w0, acc0, 0, 0, 0);
            acc1 = __builtin_amdgcn_mfma_f32_16x16x32_bf16(a, w1, acc1, 0, 0, 0);
        }

        // ---- logit partials: tanh(preact + b) * u, reduce over this wave's 32 cols ----
        // C/D layout: col = lane&15, row = (lane>>4)*4 + r   [verified mapping]
        float lp[4];
        #pragma unroll
        for (int r = 0; r < 4; ++r) {
            float v0 = fast_tanh(acc0[r] + b0) * u0;
            float v1 = fast_tanh(acc1[r] + b1) * u1;
            float v = v0 + v1;
            v += __shfl_xor(v, 1);
            v += __shfl_xor(v, 2);
            v += __shfl_xor(v, 4);
            v += __shfl_xor(v, 8);
            lp[r] = v;
        }
        if ((lane & 15) == 0) {
            int rg = lane >> 4;
            #pragma unroll
            for (int r = 0; r < 4; ++r)
                part[mt * 16 + rg * 4 + r][wave >> 1] = lp[r];
        }
        __syncthreads();  // S2: partials ready

        if (tid < ST) {
            float ev = __expf(part[tid][0] + part[tid][1]);
            e_lds[tid] = ev;
            den_acc += ev;
        }
        __syncthreads();  // S3: e ready

        // ---- phase 2: num[d] += sum_t x[t][d] * e[t]  (thread owns column d = tid) ----
        #pragma unroll
        for (int t = 0; t < ST; ++t) {
            float xv = __uint_as_float((uint32_t)lds_x[t * XS_STRIDE + tid] << 16);
            num_acc = fmaf(xv, e_lds[t], num_acc);
        }
    }

    // block-level writeback
    atomicAdd(&ws[OFF_NUM + bb * D_ + tid], num_acc);
    if (wave == 0) {
        float v = den_acc;  // lanes 0..31 hold partials, 32..63 hold 0
        v += __shfl_xor(v, 32);
        v += __shfl_xor(v, 16);
        v += __shfl_xor(v, 8);
        v += __shfl_xor(v, 4);
        v += __shfl_xor(v, 2);
        v += __shfl_xor(v, 1);
        if (lane == 0) atomicAdd(&ws[OFF_DEN + bb], v);
    }
}

// ---------------- epilogue: out = num / (den + eps) ----------------
__global__ void att_epilogue(const float* __restrict__ ws, float* __restrict__ out) {
    int bb = blockIdx.x;
    int d  = threadIdx.x;
    out[bb * D_ + d] = ws[OFF_NUM + bb * D_ + d] / (ws[OFF_DEN + bb] + EPS_);
}

extern "C" void kernel_launch(void* const* d_in, const int* in_sizes, int n_in,
                              void* d_out, int out_size, void* d_ws, size_t ws_size,
                              hipStream_t stream) {
    const float* x = (const float*)d_in[0];
    const float* W = (const float*)d_in[1];
    const float* b = (const float*)d_in[2];
    const float* u = (const float*)d_in[3];
    float* ws  = (float*)d_ws;
    float* out = (float*)d_out;

    att_prologue<<<64, 256, 0, stream>>>(W, b, u, ws);
    att_main<<<dim3(T_ / TB, B_), 256, 0, stream>>>(x, ws);
    att_epilogue<<<B_, 256, 0, stream>>>(ws, out);
}

// Round 2
// 369.799 us; speedup vs baseline: 1.0229x; 1.0229x over previous
//
#include <hip/hip_runtime.h>
#include <stdint.h>

// Problem constants (from reference setup_inputs)
#define B_    64
#define T_    4096
#define D_    256
#define A_    50
#define APAD  64     // A padded to 4 MFMA n-tiles of 16 (cols 50..63 zeroed)
#define TB    256    // T-rows per block
#define ST    32     // T-rows per subtile (2 MFMA m-tiles)
#define WT_STRIDE 264  // bf16 elems per padded row (528B; 132 words %32 = 4 -> 2-way = free)
#define XS_STRIDE 264
#define EPS_  1e-7f

// ws float layout:
//   [0      .. 16383]  num accumulator [64][256]
//   [16384 .. 16447]   den accumulator [64]
//   [16448 .. 16511]   b padded to 64
//   [16512 .. 16575]   u padded to 64
//   [16576 .. ]        Wt bf16 [64][WT_STRIDE]  (33792 bytes)
#define OFF_NUM 0
#define OFF_DEN 16384
#define OFF_B   16448
#define OFF_U   16512
#define OFF_WT  16576

typedef __attribute__((ext_vector_type(8))) short short8;
typedef __attribute__((ext_vector_type(4))) float floatx4;

__device__ __forceinline__ unsigned short f32_to_bf16(float f) {
    union { float f; uint32_t u; } v; v.f = f;
    uint32_t u = v.u;
    uint32_t r = u + 0x7FFFu + ((u >> 16) & 1u);   // RNE (inputs finite, no NaN handling needed)
    return (unsigned short)(r >> 16);
}

__device__ __forceinline__ float fast_tanh(float x) {
    float e2 = __expf(2.0f * x);
    return (e2 - 1.0f) * __builtin_amdgcn_rcpf(e2 + 1.0f);
}

// ---------------- prologue: zero accumulators, pack W/b/u ----------------
__global__ void att_prologue(const float* __restrict__ W,
                             const float* __restrict__ bias,
                             const float* __restrict__ u,
                             float* __restrict__ ws) {
    int idx = blockIdx.x * blockDim.x + threadIdx.x;
    int stride = gridDim.x * blockDim.x;
    // zero num+den
    for (int i = idx; i < OFF_DEN + B_; i += stride) ws[i] = 0.0f;
    // padded b, u
    for (int i = idx; i < APAD; i += stride) {
        ws[OFF_B + i] = (i < A_) ? bias[i] : 0.0f;
        ws[OFF_U + i] = (i < A_) ? u[i]    : 0.0f;
    }
    // W [256][50] fp32 -> Wt bf16 [64][WT_STRIDE] (transposed, col-padded with 0)
    unsigned short* wt = (unsigned short*)(ws + OFF_WT);
    for (int i = idx; i < APAD * D_; i += stride) {
        int a = i >> 8;          // 0..63
        int k = i & 255;         // 0..255
        float val = (a < A_) ? W[k * A_ + a] : 0.0f;
        wt[a * WT_STRIDE + k] = f32_to_bf16(val);
    }
}

// ---------------- main fused kernel ----------------
__global__ __launch_bounds__(256) void att_main(const float* __restrict__ x,
                                                float* __restrict__ ws) {
    __shared__ unsigned short lds_wt[APAD * WT_STRIDE];  // 33792 B
    __shared__ unsigned short lds_x[ST * XS_STRIDE];     // 16896 B
    __shared__ float part[ST][2];
    __shared__ float e_lds[ST];

    const int tid  = threadIdx.x;
    const int wave = tid >> 6;
    const int lane = tid & 63;
    const int bb   = blockIdx.y;   // batch
    const int tblk = blockIdx.x;   // T-tile

    const float* xblk = x + ((size_t)bb * T_ + (size_t)tblk * TB) * D_;

    // ---- prefetch subtile 0 into registers (issue before anything else) ----
    float4 r[8];
    {
        const float4* xg = (const float4*)xblk;
        #pragma unroll
        for (int i = 0; i < 8; ++i) r[i] = xg[tid + (i << 8)];
    }

    // stage packed Wt (bf16 image, contiguous) into LDS: 33792 B = 2112 uint4
    {
        const uint4* g = (const uint4*)(ws + OFF_WT);
        uint4* l = (uint4*)lds_wt;
        for (int i = tid; i < (APAD * WT_STRIDE * 2) / 16; i += 256) l[i] = g[i];
    }

    // per-wave tile assignment: mt = m-tile (rows), nt0/nt1 = n-tiles (cols)
    const int mt  = wave & 1;
    const int nt0 = (wave >> 1) * 2, nt1 = nt0 + 1;
    const int c0  = nt0 * 16 + (lane & 15);
    const int c1  = nt1 * 16 + (lane & 15);
    const float b0 = ws[OFF_B + c0], b1 = ws[OFF_B + c1];
    const float u0 = ws[OFF_U + c0], u1 = ws[OFF_U + c1];

    float num_acc = 0.0f;   // thread tid owns output column d = tid
    float den_acc = 0.0f;   // only tid < ST accumulate

    const int arow_off = (mt * 16 + (lane & 15)) * XS_STRIDE;
    const int koff     = (lane >> 4) * 8;
    const int brow0    = (nt0 * 16 + (lane & 15)) * WT_STRIDE;
    const int brow1    = (nt1 * 16 + (lane & 15)) * WT_STRIDE;

    for (int st = 0; st < TB / ST; ++st) {
        __syncthreads();  // S0: lds_x free (prev phase-2 readers done); Wt staged on st=0

        // ---- phase 1: registers (prefetched) -> bf16 LDS tile (32 x 256) ----
        #pragma unroll
        for (int i = 0; i < 8; ++i) {
            int f = tid + (i << 8);          // float4 index in tile
            int row = f >> 6;
            int col4 = f & 63;
            uint32_t p0 = ((uint32_t)f32_to_bf16(r[i].y) << 16) | f32_to_bf16(r[i].x);
            uint32_t p1 = ((uint32_t)f32_to_bf16(r[i].w) << 16) | f32_to_bf16(r[i].z);
            uint32_t* dst = (uint32_t*)&lds_x[row * XS_STRIDE + col4 * 4];
            dst[0] = p0; dst[1] = p1;
        }
        __syncthreads();  // S1: x tile ready

        // ---- issue next subtile's global loads NOW (in flight across compute) ----
        if (st < TB / ST - 1) {
            const float4* xn = (const float4*)(xblk + (st + 1) * ST * D_);
            #pragma unroll
            for (int i = 0; i < 8; ++i) r[i] = xn[tid + (i << 8)];
        }

        // ---- MFMA: preact[32 x 64] = x_tile[32x256] * Wt^T ----
        floatx4 acc0 = {0.f, 0.f, 0.f, 0.f};
        floatx4 acc1 = {0.f, 0.f, 0.f, 0.f};
        #pragma unroll
        for (int ks = 0; ks < 8; ++ks) {
            short8 a  = *(const short8*)&lds_x[arow_off + ks * 32 + koff];
            short8 w0 = *(const short8*)&lds_wt[brow0 + ks * 32 + koff];
            short8 w1 = *(const short8*)&lds_wt[brow1 + ks * 32 + koff];
            acc0 = __builtin_amdgcn_mfma_f32_16x16x32_bf16(a, w0, acc0, 0, 0, 0);
            acc1 = __builtin_amdgcn_mfma_f32_16x16x32_bf16(a, w1, acc1, 0, 0, 0);
        }

        // ---- logit partials: tanh(preact + b) * u, reduce over this wave's 32 cols ----
        // C/D layout: col = lane&15, row = (lane>>4)*4 + r
        float lp[4];
        #pragma unroll
        for (int rr = 0; rr < 4; ++rr) {
            float v0 = fast_tanh(acc0[rr] + b0) * u0;
            float v1 = fast_tanh(acc1[rr] + b1) * u1;
            float v = v0 + v1;
            v += __shfl_xor(v, 1);
            v += __shfl_xor(v, 2);
            v += __shfl_xor(v, 4);
            v += __shfl_xor(v, 8);
            lp[rr] = v;
        }
        if ((lane & 15) == 0) {
            int rg = lane >> 4;
            #pragma unroll
            for (int rr = 0; rr < 4; ++rr)
                part[mt * 16 + rg * 4 + rr][wave >> 1] = lp[rr];
        }
        __syncthreads();  // S2: partials ready

        if (tid < ST) {
            float ev = __expf(part[tid][0] + part[tid][1]);
            e_lds[tid] = ev;
            den_acc += ev;
        }
        __syncthreads();  // S3: e ready

        // ---- phase 2: num[d] += sum_t x[t][d] * e[t]  (thread owns column d = tid) ----
        #pragma unroll
        for (int t = 0; t < ST; ++t) {
            float xv = __uint_as_float((uint32_t)lds_x[t * XS_STRIDE + tid] << 16);
            num_acc = fmaf(xv, e_lds[t], num_acc);
        }
    }

    // block-level writeback
    atomicAdd(&ws[OFF_NUM + bb * D_ + tid], num_acc);
    if (wave == 0) {
        float v = den_acc;  // lanes 0..31 hold partials, 32..63 hold 0
        v += __shfl_xor(v, 32);
        v += __shfl_xor(v, 16);
        v += __shfl_xor(v, 8);
        v += __shfl_xor(v, 4);
        v += __shfl_xor(v, 2);
        v += __shfl_xor(v, 1);
        if (lane == 0) atomicAdd(&ws[OFF_DEN + bb], v);
    }
}

// ---------------- epilogue: out = num / (den + eps) ----------------
__global__ void att_epilogue(const float* __restrict__ ws, float* __restrict__ out) {
    int bb = blockIdx.x;
    int d  = threadIdx.x;
    out[bb * D_ + d] = ws[OFF_NUM + bb * D_ + d] / (ws[OFF_DEN + bb] + EPS_);
}

extern "C" void kernel_launch(void* const* d_in, const int* in_sizes, int n_in,
                              void* d_out, int out_size, void* d_ws, size_t ws_size,
                              hipStream_t stream) {
    const float* x = (const float*)d_in[0];
    const float* W = (const float*)d_in[1];
    const float* b = (const float*)d_in[2];
    const float* u = (const float*)d_in[3];
    float* ws  = (float*)d_ws;
    float* out = (float*)d_out;

    att_prologue<<<64, 256, 0, stream>>>(W, b, u, ws);
    att_main<<<dim3(T_ / TB, B_), 256, 0, stream>>>(x, ws);
    att_epilogue<<<B_, 256, 0, stream>>>(ws, out);
}

// Round 3
// 366.743 us; speedup vs baseline: 1.0314x; 1.0083x over previous
//
#include <hip/hip_runtime.h>
#include <stdint.h>

// Problem constants (from reference setup_inputs)
#define B_    64
#define T_    4096
#define D_    256
#define A_    50
#define APAD  64     // A padded to 4 MFMA n-tiles of 16 (cols 50..63 zeroed)
#define TB    256    // T-rows per block
#define ST    32     // T-rows per subtile (2 MFMA m-tiles)
#define WT_STRIDE 264  // bf16 elems per padded W row
#define XS_STRIDE 264  // bf16 elems per padded x row (528B; row shift = 4 banks)
#define EPS_  1e-7f

// ws float layout:
//   [0      .. 16383]  num accumulator [64][256]
//   [16384 .. 16447]   den accumulator [64]
//   [16448 .. 16511]   b padded to 64
//   [16512 .. 16575]   u padded to 64
//   [16576 .. ]        Wt bf16 [64][WT_STRIDE]
#define OFF_NUM 0
#define OFF_DEN 16384
#define OFF_B   16448
#define OFF_U   16512
#define OFF_WT  16576

typedef __attribute__((ext_vector_type(8))) short short8;
typedef __attribute__((ext_vector_type(4))) float floatx4;

__device__ __forceinline__ unsigned short f32_to_bf16(float f) {
    union { float f; uint32_t u; } v; v.f = f;
    uint32_t u = v.u;
    uint32_t r = u + 0x7FFFu + ((u >> 16) & 1u);   // RNE (inputs finite)
    return (unsigned short)(r >> 16);
}

__device__ __forceinline__ float fast_tanh(float x) {
    float e2 = __expf(2.0f * x);
    return (e2 - 1.0f) * __builtin_amdgcn_rcpf(e2 + 1.0f);
}

// ---------------- prologue: zero accumulators, pack W/b/u ----------------
__global__ void att_prologue(const float* __restrict__ W,
                             const float* __restrict__ bias,
                             const float* __restrict__ u,
                             float* __restrict__ ws) {
    int idx = blockIdx.x * blockDim.x + threadIdx.x;
    int stride = gridDim.x * blockDim.x;
    for (int i = idx; i < OFF_DEN + B_; i += stride) ws[i] = 0.0f;
    for (int i = idx; i < APAD; i += stride) {
        ws[OFF_B + i] = (i < A_) ? bias[i] : 0.0f;
        ws[OFF_U + i] = (i < A_) ? u[i]    : 0.0f;
    }
    // W [256][50] fp32 -> Wt bf16 [64][WT_STRIDE] (transposed, col-padded with 0)
    unsigned short* wt = (unsigned short*)(ws + OFF_WT);
    for (int i = idx; i < APAD * D_; i += stride) {
        int a = i >> 8;          // 0..63
        int k = i & 255;         // 0..255
        float val = (a < A_) ? W[k * A_ + a] : 0.0f;
        wt[a * WT_STRIDE + k] = f32_to_bf16(val);
    }
}

// ---------------- main fused kernel ----------------
// 4 waves/block: wave w owns n-tile w (cols 16w..16w+15), both m-tiles.
// B-fragments of W live in registers (32 VGPR/wave), loaded once.
__global__ __launch_bounds__(256, 4) void att_main(const float* __restrict__ x,
                                                   float* __restrict__ ws) {
    __shared__ unsigned short lds_x[ST * XS_STRIDE];  // 16896 B
    __shared__ float part[ST][4];
    __shared__ float e_lds[ST];

    const int tid  = threadIdx.x;
    const int wave = tid >> 6;
    const int lane = tid & 63;
    const int bb   = blockIdx.y;   // batch
    const int tblk = blockIdx.x;   // T-tile

    const float* xblk = x + ((size_t)bb * T_ + (size_t)tblk * TB) * D_;

    // ---- prefetch subtile 0: each thread grabs 8 contiguous floats x4 ----
    float4 r[8];
    {
        const float4* xg = (const float4*)xblk;
        #pragma unroll
        for (int i = 0; i < 4; ++i) {
            r[2 * i]     = xg[2 * tid + 512 * i];
            r[2 * i + 1] = xg[2 * tid + 512 * i + 1];
        }
    }

    // ---- load this wave's B-fragments (n-tile = wave) into registers ----
    short8 bw[8];
    {
        const unsigned short* wt = (const unsigned short*)(ws + OFF_WT);
        const unsigned short* wrow = wt + (wave * 16 + (lane & 15)) * WT_STRIDE
                                        + ((lane >> 4) * 8);
        #pragma unroll
        for (int ks = 0; ks < 8; ++ks)
            bw[ks] = *(const short8*)(wrow + ks * 32);
    }

    const int c = wave * 16 + (lane & 15);
    const float b_c = ws[OFF_B + c];
    const float u_c = ws[OFF_U + c];

    float num_acc = 0.0f;   // thread tid owns output column d = tid
    float den_acc = 0.0f;   // only tid < ST accumulate

    const int arow0 = (lane & 15) * XS_STRIDE;          // m-tile 0
    const int arow1 = (16 + (lane & 15)) * XS_STRIDE;   // m-tile 1
    const int koff  = (lane >> 4) * 8;
    const int wrow_lds = (tid >> 5) * XS_STRIDE + (tid & 31) * 8;  // phase-1 dest base

    for (int st = 0; st < TB / ST; ++st) {
        __syncthreads();  // S0: lds_x free (prev phase-2 readers done)

        // ---- phase 1: regs -> bf16 LDS tile, one ds_write_b128 per i ----
        #pragma unroll
        for (int i = 0; i < 4; ++i) {
            uint4 p;
            p.x = ((uint32_t)f32_to_bf16(r[2*i].y)   << 16) | f32_to_bf16(r[2*i].x);
            p.y = ((uint32_t)f32_to_bf16(r[2*i].w)   << 16) | f32_to_bf16(r[2*i].z);
            p.z = ((uint32_t)f32_to_bf16(r[2*i+1].y) << 16) | f32_to_bf16(r[2*i+1].x);
            p.w = ((uint32_t)f32_to_bf16(r[2*i+1].w) << 16) | f32_to_bf16(r[2*i+1].z);
            *(uint4*)&lds_x[wrow_lds + i * 8 * XS_STRIDE] = p;
        }
        __syncthreads();  // S1: x tile ready

        // ---- issue next subtile's global loads (in flight across MFMA) ----
        if (st < TB / ST - 1) {
            const float4* xn = (const float4*)(xblk + (st + 1) * ST * D_);
            #pragma unroll
            for (int i = 0; i < 4; ++i) {
                r[2 * i]     = xn[2 * tid + 512 * i];
                r[2 * i + 1] = xn[2 * tid + 512 * i + 1];
            }
        }

        // ---- MFMA: preact[32 x 16] for this wave's n-tile ----
        floatx4 acc0 = {0.f, 0.f, 0.f, 0.f};
        floatx4 acc1 = {0.f, 0.f, 0.f, 0.f};
        #pragma unroll
        for (int ks = 0; ks < 8; ++ks) {
            short8 a0 = *(const short8*)&lds_x[arow0 + ks * 32 + koff];
            short8 a1 = *(const short8*)&lds_x[arow1 + ks * 32 + koff];
            acc0 = __builtin_amdgcn_mfma_f32_16x16x32_bf16(a0, bw[ks], acc0, 0, 0, 0);
            acc1 = __builtin_amdgcn_mfma_f32_16x16x32_bf16(a1, bw[ks], acc1, 0, 0, 0);
        }

        // ---- logit partials: tanh(preact + b) * u, reduce over 16 cols ----
        // C/D layout: col = lane&15, row = (lane>>4)*4 + rr
        float lp0[4], lp1[4];
        #pragma unroll
        for (int rr = 0; rr < 4; ++rr) {
            float v0 = fast_tanh(acc0[rr] + b_c) * u_c;
            float v1 = fast_tanh(acc1[rr] + b_c) * u_c;
            v0 += __shfl_xor(v0, 1); v1 += __shfl_xor(v1, 1);
            v0 += __shfl_xor(v0, 2); v1 += __shfl_xor(v1, 2);
            v0 += __shfl_xor(v0, 4); v1 += __shfl_xor(v1, 4);
            v0 += __shfl_xor(v0, 8); v1 += __shfl_xor(v1, 8);
            lp0[rr] = v0; lp1[rr] = v1;
        }
        if ((lane & 15) == 0) {
            int rg = lane >> 4;
            #pragma unroll
            for (int rr = 0; rr < 4; ++rr) {
                part[rg * 4 + rr][wave]      = lp0[rr];
                part[16 + rg * 4 + rr][wave] = lp1[rr];
            }
        }
        __syncthreads();  // S2: partials ready

        if (tid < ST) {
            float ev = __expf(part[tid][0] + part[tid][1] + part[tid][2] + part[tid][3]);
            e_lds[tid] = ev;
            den_acc += ev;
        }
        __syncthreads();  // S3: e ready

        // ---- phase 2: num[d] += sum_t x[t][d] * e[t] ----
        #pragma unroll
        for (int t = 0; t < ST; ++t) {
            float xv = __uint_as_float((uint32_t)lds_x[t * XS_STRIDE + tid] << 16);
            num_acc = fmaf(xv, e_lds[t], num_acc);
        }
    }

    // block-level writeback
    atomicAdd(&ws[OFF_NUM + bb * D_ + tid], num_acc);
    if (wave == 0) {
        float v = den_acc;  // lanes 0..31 hold partials, 32..63 hold 0
        v += __shfl_xor(v, 32);
        v += __shfl_xor(v, 16);
        v += __shfl_xor(v, 8);
        v += __shfl_xor(v, 4);
        v += __shfl_xor(v, 2);
        v += __shfl_xor(v, 1);
        if (lane == 0) atomicAdd(&ws[OFF_DEN + bb], v);
    }
}

// ---------------- epilogue: out = num / (den + eps) ----------------
__global__ void att_epilogue(const float* __restrict__ ws, float* __restrict__ out) {
    int bb = blockIdx.x;
    int d  = threadIdx.x;
    out[bb * D_ + d] = ws[OFF_NUM + bb * D_ + d] / (ws[OFF_DEN + bb] + EPS_);
}

extern "C" void kernel_launch(void* const* d_in, const int* in_sizes, int n_in,
                              void* d_out, int out_size, void* d_ws, size_t ws_size,
                              hipStream_t stream) {
    const float* x = (const float*)d_in[0];
    const float* W = (const float*)d_in[1];
    const float* b = (const float*)d_in[2];
    const float* u = (const float*)d_in[3];
    float* ws  = (float*)d_ws;
    float* out = (float*)d_out;

    att_prologue<<<64, 256, 0, stream>>>(W, b, u, ws);
    att_main<<<dim3(T_ / TB, B_), 256, 0, stream>>>(x, ws);
    att_epilogue<<<B_, 256, 0, stream>>>(ws, out);
}